// Round 15
// baseline (748.131 us; speedup 1.0000x reference)
//
#include <hip/hip_runtime.h>

// ScaledDotProductAttention: B=2,H=16,S=2048,DK=DV=64, fp32 in/out, mask (True => -1e9).
// R22 = R21 (measured best: 747.2us) + counted-vmcnt barrier + 2-deep mask prefetch.
//   Mechanism (T3/T4, m201-verified pattern): __syncthreads drains vmcnt(0) -- including
//   the register-destined mask loads issued THIS phase but needed NEXT phase (~300cy
//   of exposed HBM latency per barrier, all waves). Replace with
//   `s_waitcnt vmcnt(2)` + raw s_barrier: the 2 youngest outstanding VMEM ops are
//   exactly the 2 mask loads (VGPR destination -> no cross-wave hazard); the 4
//   LDS-writing glds are always fully drained, so tile visibility is unchanged.
//   Mask prefetch goes 2-deep (slots A/B, loop unrolled x2 for static regs) so each
//   mask has ~2 compute phases of cover. VMEM issue order (glds then mask) pinned
//   with zero-cost memory-clobber asm; tail peeled (it=31 uses vmcnt(0)).
//   Ladder: R8 757.8 / R17 751.5 / R20 749.2 / R21 747.2. Wave-split retired (776-787).
//   Pre-commit: >=746.5 => null => declare roofline next round.

#define LOG2E 1.4426950408889634f
#define QSCALE (0.125f * LOG2E)          // fold 1/sqrt(64) and log2(e) into Q

typedef __attribute__((ext_vector_type(8))) short short8;   // 8 x bf16
typedef __attribute__((ext_vector_type(4))) short short4v;  // 4 x bf16
typedef __attribute__((ext_vector_type(4))) float f32x4;    // MFMA acc
typedef unsigned __attribute__((ext_vector_type(4))) uintv4;

constexpr int S = 2048, D = 64;

__device__ __forceinline__ short bf16rne(float x) {
  union { float f; unsigned u; } cv; cv.f = x;
  unsigned u = cv.u;
  u += 0x7fffu + ((u >> 16) & 1u);
  return (short)(u >> 16);
}

__device__ __forceinline__ void glds16(const void* g, void* l) {
  __builtin_amdgcn_global_load_lds(
      (const __attribute__((address_space(1))) void*)g,
      (__attribute__((address_space(3))) void*)l, 16, 0, 0);
}

// Merged prep: blocks [0,2048) convert K fp32->bf16; [2048,3072) build bf16 V^T.
// Block 0 wave 0 additionally detects mask format: 1 = byte-packed, 0 = 4-byte elems.
__global__ void prep(const float* __restrict__ kp, const float* __restrict__ vp,
                     short* __restrict__ kb, short* __restrict__ vt,
                     const unsigned* __restrict__ m, int* __restrict__ flag) {
  const int b = blockIdx.x;
  const int tid = threadIdx.x;
  if (b == 0 && tid < 64) {
    unsigned v = m[tid];
    unsigned long long big = __ballot(v > 1u && v != 0x3F800000u);
    unsigned long long isf = __ballot(v == 0x3F800000u);
    if (tid == 0) *flag = (big != 0ull && isf == 0ull) ? 1 : 0;
  }
  if (b < 2048) {
    size_t i = ((size_t)b * 256 + tid) * 8;
    float4 a = *(const float4*)(kp + i);
    float4 c = *(const float4*)(kp + i + 4);
    short8 s;
    s[0] = bf16rne(a.x); s[1] = bf16rne(a.y); s[2] = bf16rne(a.z); s[3] = bf16rne(a.w);
    s[4] = bf16rne(c.x); s[5] = bf16rne(c.y); s[6] = bf16rne(c.z); s[7] = bf16rne(c.w);
    *(short8*)&kb[i] = s;
  } else {
    __shared__ float tile[64][65];
    const int bb = b - 2048;
    const int bh = bb >> 5, k0 = (bb & 31) * 64;
    const float* src = vp + ((size_t)(bh * S + k0)) * D;
#pragma unroll
    for (int i = 0; i < 4; ++i) {
      int row = i * 16 + (tid >> 4);
      int col = (tid & 15) * 4;
      float4 x = *(const float4*)(src + row * D + col);
      tile[row][col] = x.x; tile[row][col + 1] = x.y;
      tile[row][col + 2] = x.z; tile[row][col + 3] = x.w;
    }
    __syncthreads();
#pragma unroll
    for (int i = 0; i < 4; ++i) {
      int dim = i * 16 + (tid >> 4);
      int kb4 = (tid & 15) * 4;
      short4v s;
#pragma unroll
      for (int j = 0; j < 4; ++j) s[j] = bf16rne(tile[kb4 + j][dim]);
      *(short4v*)&vt[((size_t)(bh * D + dim)) * S + k0 + kb4] = s;
    }
  }
}

__launch_bounds__(256, 4)
__global__ void attn_fwd(const float* __restrict__ qp, const short* __restrict__ kb,
                         const short* __restrict__ vt, const void* __restrict__ mp,
                         float* __restrict__ op, const int* __restrict__ fmtp) {
  const int fmt  = *fmtp;
  const int tid  = threadIdx.x;
  const int lane = tid & 63;
  const int w    = tid >> 6;          // wave 0..3
  const int c    = lane & 15;
  const int quad = lane >> 4;

  const int bh = blockIdx.x >> 5;
  const int q0 = (blockIdx.x & 31) * 64;

  __shared__ short ks[2][64 * 64];    // K tile [key][dim], swz: pos p row r holds
                                      //   global chunk p ^ (r&7) ^ (((r>>3)&1)<<2)
  __shared__ short vs[2][64 * 64];    // V^T tile [dim][key], swz: p ^ (r&7) (R8)

  // ---- Q B-fragments: lane n=c is q-row q0+w*16+c ----
  const float* qg = qp + ((size_t)(bh * S + q0 + w * 16 + c)) * D;
  short8 qB[2];
#pragma unroll
  for (int kk = 0; kk < 2; ++kk) {
    const float* p = qg + kk * 32 + quad * 8;
    float4 x = *(const float4*)(p);
    float4 y = *(const float4*)(p + 4);
    short8 f;
    f[0] = bf16rne(x.x * QSCALE); f[1] = bf16rne(x.y * QSCALE);
    f[2] = bf16rne(x.z * QSCALE); f[3] = bf16rne(x.w * QSCALE);
    f[4] = bf16rne(y.x * QSCALE); f[5] = bf16rne(y.y * QSCALE);
    f[6] = bf16rne(y.z * QSCALE); f[7] = bf16rne(y.w * QSCALE);
    qB[kk] = f;
  }

  f32x4 O[4];
#pragma unroll
  for (int t = 0; t < 4; ++t) O[t] = (f32x4){0.f, 0.f, 0.f, 0.f};
  f32x4 Lv = (f32x4){0.f, 0.f, 0.f, 0.f};   // 4 independent L chains (R21)

  // staging geometry (R8): slot=(h2*4+w)*64+lane; row=(h2*4+w)*8+(lane>>3)
  const int rsub = lane >> 3;
  const int cswV = (lane & 7) ^ rsub;                 // V swizzle (R8)
  const int cswK = cswV ^ ((w & 1) << 2);             // K swizzle: row-bit3 spread (R17)
  const short* kbase = kb + ((size_t)(bh * S)) * D;
  const short* vbase = vt + ((size_t)(bh * D)) * S;

  const int sw0 = ((quad    ) ^ (c & 7)) * 8;         // V-read positions (R8)
  const int sw1 = ((quad | 4) ^ (c & 7)) * 8;
  const int kx  = (((c >> 2) & 1) << 2);              // K-read row-bit3 term

  const size_t mrow = ((size_t)(bh * S + q0 + w * 16 + c)) * S;

  unsigned long long mmA0, mmA1, mmB0, mmB1;   // 2-deep mask slots (A=even, B=odd it)

  auto stage = [&](int it, int buf) {
    const int k0 = it * 64;
#pragma unroll
    for (int h2 = 0; h2 < 2; ++h2) {
      const int row = (h2 * 4 + w) * 8 + rsub;
      glds16(kbase + (size_t)(k0 + row) * 64 + cswK * 8,
             (char*)&ks[buf][0] + (h2 * 4 + w) * 1024);
      glds16(vbase + (size_t)row * S + k0 + cswV * 8,
             (char*)&vs[buf][0] + (h2 * 4 + w) * 1024);
    }
  };

  auto mload = [&](unsigned long long& d0, unsigned long long& d1, int it) {
    const int kO = it * 64;
    if (fmt == 1) {
      const unsigned char* mq = (const unsigned char*)mp + mrow + kO + 8 * quad;
      d0 = __builtin_nontemporal_load((const unsigned long long*)mq);
      d1 = __builtin_nontemporal_load((const unsigned long long*)(mq + 32));
    } else {
#pragma unroll
      for (int h = 0; h < 2; ++h) {
        const unsigned* m0 = (const unsigned*)mp + mrow + kO + h * 32 + 8 * quad;
        uintv4 a = __builtin_nontemporal_load((const uintv4*)m0);
        uintv4 b = __builtin_nontemporal_load((const uintv4*)(m0 + 4));
        unsigned long long t = 0ull;
#pragma unroll
        for (int j = 0; j < 4; ++j) {
          if (a[j]) t |= 0xffull << (8 * j);
          if (b[j]) t |= 0xffull << (8 * (j + 4));
        }
        if (h == 0) d0 = t; else d1 = t;
      }
    }
  };

  // compute cluster (R21 body): scores w/ permuted A-rows -> pa in regs -> PV
  auto compute = [&](int buf, unsigned long long mb0, unsigned long long mb1) {
    __builtin_amdgcn_s_setprio(1);
    short8 pa0, pa1;
#pragma unroll
    for (int g = 0; g < 4; ++g) {
      const int r7 = (c & 3) + 4 * (g & 1);           // rr & 7
      const int rr = ((g & 2) << 4) + 8 * (c >> 2) + r7;
      const int px = ((quad ^ r7 ^ kx)) * 8;          // chunk pos for dims 8*quad..
      short8 ka0 = *(const short8*)&ks[buf][rr * 64 + px];
      short8 ka1 = *(const short8*)&ks[buf][rr * 64 + (px ^ 32)];
      f32x4 z = (f32x4){0.f, 0.f, 0.f, 0.f};
      z = __builtin_amdgcn_mfma_f32_16x16x32_bf16(ka0, qB[0], z, 0, 0, 0);
      z = __builtin_amdgcn_mfma_f32_16x16x32_bf16(ka1, qB[1], z, 0, 0, 0);
      const unsigned long long mq64 = (g & 2) ? mb1 : mb0;
      const unsigned mw = (g & 1) ? (unsigned)(mq64 >> 32) : (unsigned)mq64;
#pragma unroll
      for (int r = 0; r < 4; ++r) {
        const int j = 4 * (g & 1) + r;
        float e = ((mw >> (8 * r)) & 0xffu) ? 0.f : exp2f(z[r]);
        Lv[r] += e;
        if (g & 2) pa1[j] = bf16rne(e); else pa0[j] = bf16rne(e);
      }
    }
#pragma unroll
    for (int t = 0; t < 4; ++t) {
      short8 vb0 = *(const short8*)&vs[buf][(16 * t + c) * 64 + sw0];
      short8 vb1 = *(const short8*)&vs[buf][(16 * t + c) * 64 + sw1];
      O[t] = __builtin_amdgcn_mfma_f32_16x16x32_bf16(pa0, vb0, O[t], 0, 0, 0);
      O[t] = __builtin_amdgcn_mfma_f32_16x16x32_bf16(pa1, vb1, O[t], 0, 0, 0);
    }
    __builtin_amdgcn_s_setprio(0);
  };

  // ---- prologue: glds(0) then mask(0), mask(1) (order pinned) ----
  stage(0, 0);
  asm volatile("" ::: "memory");
  mload(mmA0, mmA1, 0);
  mload(mmB0, mmB1, 1);

  // ---- main: 15 pairs (it = 0..29), counted-vmcnt barriers ----
  // Entering iter it: outstanding VMEM (oldest first) = glds(it) x4, mask(it+1) x2.
  // vmcnt(2) retires glds(it) (LDS tile visible after barrier) and leaves the two
  // register-destined mask loads in flight.
#pragma unroll 1
  for (int ip = 0; ip < 15; ++ip) {
    const int itE = 2 * ip;
    // even iter (buf 0, slot A)
    asm volatile("s_waitcnt vmcnt(2)" ::: "memory");
    __builtin_amdgcn_s_barrier();
    stage(itE + 1, 1);
    asm volatile("" ::: "memory");
    {
      const unsigned long long b0 = mmA0, b1 = mmA1;
      mload(mmA0, mmA1, itE + 2);
      compute(0, b0, b1);
    }
    // odd iter (buf 1, slot B)
    asm volatile("s_waitcnt vmcnt(2)" ::: "memory");
    __builtin_amdgcn_s_barrier();
    stage(itE + 2, 0);
    asm volatile("" ::: "memory");
    {
      const unsigned long long b0 = mmB0, b1 = mmB1;
      mload(mmB0, mmB1, itE + 3);
      compute(1, b0, b1);
    }
  }
  // ---- peeled tail: it = 30 (buf 0, slot A), it = 31 (buf 1, slot B) ----
  asm volatile("s_waitcnt vmcnt(2)" ::: "memory");   // glds(30) drained; mask(31) flies
  __builtin_amdgcn_s_barrier();
  stage(31, 1);
  {
    const unsigned long long b0 = mmA0, b1 = mmA1;   // mask(30), loaded at it=28
    compute(0, b0, b1);
  }
  asm volatile("s_waitcnt vmcnt(0)" ::: "memory");   // final: drain glds(31) (+mask(31))
  __builtin_amdgcn_s_barrier();
  {
    const unsigned long long b0 = mmB0, b1 = mmB1;   // mask(31)
    compute(1, b0, b1);
  }

  // ---- epilogue: single deferred L reduction, then O/L (R21) ----
  float Lt = (Lv[0] + Lv[1]) + (Lv[2] + Lv[3]);
  Lt += __shfl_xor(Lt, 16);
  Lt += __shfl_xor(Lt, 32);
#pragma unroll
  for (int r = 0; r < 4; ++r) {
    float Lr = __shfl(Lt, (lane & 48) | (quad * 4 + r));
    float inv = 1.f / Lr;
    const size_t ob = ((size_t)(bh * S + q0 + w * 16 + quad * 4 + r)) * D;
#pragma unroll
    for (int t = 0; t < 4; ++t) op[ob + 16 * t + c] = O[t][r] * inv;
  }
}

extern "C" void kernel_launch(void* const* d_in, const int* in_sizes, int n_in,
                              void* d_out, int out_size, void* d_ws, size_t ws_size,
                              hipStream_t stream) {
  const float* q = (const float*)d_in[0];
  const float* k = (const float*)d_in[1];
  const float* v = (const float*)d_in[2];
  const void*  m = d_in[3];

  short* kbuf = (short*)d_ws;                         // 8 MiB bf16 K
  short* vtb  = (short*)((char*)d_ws + (8u << 20));   // 8 MiB bf16 V^T
  int* flag   = (int*)((char*)d_ws + (16u << 20));

  prep<<<3072, 256, 0, stream>>>(k, v, kbuf, vtb, (const unsigned*)m, flag);
  attn_fwd<<<1024, 256, 0, stream>>>(q, kbuf, vtb, m, (float*)d_out, flag);
}